// Round 8
// baseline (189.693 us; speedup 1.0000x reference)
//
#include <hip/hip_runtime.h>
#include <hip/hip_fp16.h>

#define N_NODES 50000
#define N_EDGES 800000
// D_FEAT=64, D_EDGE=16, D_HID=16, D_MSG=64, D_OUT=64

#define NBu 784    // 64-node buckets: 784*64 = 50176 >= 50000
#define BSH 6      // bucket = dst >> 6
#define PB  256    // chist/partition blocks
#define EPB 3125   // edges per partition block (256*3125 = 800000 exact)
#define PITERS 13  // ceil(3125/256)

__device__ __forceinline__ unsigned fkey(float f) {
    unsigned u = __float_as_uint(f);
    return (u & 0x80000000u) ? ~u : (u | 0x80000000u);
}
#define KEY_NEG_INF 0x007FFFFFu  // key(-inf)

// wave-local LDS fence (per-wave private LDS region; DS pipe in-order per wave)
__device__ __forceinline__ void wave_lds_fence() {
    asm volatile("s_waitcnt lgkmcnt(0)" ::: "memory");
    __builtin_amdgcn_sched_barrier(0);
}

// block-wide exclusive scan of 256 values (one per thread). Uniform call only.
__device__ __forceinline__ unsigned block_exscan256(unsigned v, unsigned* wsum,
                                                    unsigned* chunkTot) {
    const int t = threadIdx.x, lane = t & 63, w = t >> 6;
    unsigned inc = v;
#pragma unroll
    for (int d = 1; d < 64; d <<= 1) {
        unsigned n = __shfl_up(inc, d, 64);
        if (lane >= d) inc += n;
    }
    if (lane == 63) wsum[w] = inc;
    __syncthreads();
    unsigned woff = 0;
#pragma unroll
    for (int i = 0; i < 3; ++i) if (i < w) woff += wsum[i];
    if (chunkTot && t == 255) *chunkTot = woff + inc;
    __syncthreads();
    return woff + inc - v;
}

// ---------------- chist + xw ----------------
// hist of dst>>6 into bcnt[block][NBu]; xw[v] = b1 + x[v] @ W1[16:]
__global__ __launch_bounds__(256) void chist_xw_kernel(
    const int* __restrict__ dst, unsigned* __restrict__ bcnt,
    const float* __restrict__ x, const float* __restrict__ W1,
    const float* __restrict__ b1, float* __restrict__ xw)
{
    __shared__ unsigned lh[NBu];
    const int t = threadIdx.x, b = blockIdx.x;
    for (int i = t; i < NBu; i += 256) lh[i] = 0u;
    __syncthreads();
    const int e0 = b * EPB;
#pragma unroll
    for (int it = 0; it < PITERS; ++it) {
        const int i = it * 256 + t;
        if (i < EPB) atomicAdd(&lh[(unsigned)dst[e0 + i] >> BSH], 1u);
    }
    __syncthreads();
    for (int i = t; i < NBu; i += 256) bcnt[(size_t)b * NBu + i] = lh[i];

    if (b < 196) {
        const int v = b * 256 + t;
        if (v < N_NODES) {
            float acc[16];
#pragma unroll
            for (int k = 0; k < 16; ++k) acc[k] = b1[k];
            const float4* xp = reinterpret_cast<const float4*>(x) + (size_t)v * 16;
#pragma unroll
            for (int c = 0; c < 16; ++c) {
                float4 tv = xp[c];
                const float xv[4] = {tv.x, tv.y, tv.z, tv.w};
#pragma unroll
                for (int q = 0; q < 4; ++q) {
                    const int row = 16 + 4 * c + q;
#pragma unroll
                    for (int k = 0; k < 16; ++k)
                        acc[k] = fmaf(xv[q], W1[row * 16 + k], acc[k]);
                }
            }
            float4* op = reinterpret_cast<float4*>(xw) + (size_t)v * 4;
#pragma unroll
            for (int c = 0; c < 4; ++c) {
                float4 o; o.x = acc[4*c]; o.y = acc[4*c+1]; o.z = acc[4*c+2]; o.w = acc[4*c+3];
                op[c] = o;
            }
        }
    }
}

// ---------------- cscanA: per-bucket column scan over the 256 blocks -------
__global__ __launch_bounds__(256) void cscanA_kernel(const unsigned* __restrict__ bcnt,
                                                     unsigned* __restrict__ gstart,
                                                     unsigned* __restrict__ tot) {
    __shared__ unsigned wsum[4];
    const int t = threadIdx.x, bu = blockIdx.x;
    const unsigned v = bcnt[(size_t)t * NBu + bu];
    const unsigned excl = block_exscan256(v, wsum, nullptr);
    gstart[(size_t)t * NBu + bu] = excl;
    if (t == 255) tot[bu] = excl + v;
}

// ---------------- cscanB: boffG = exscan(tot[784]) -------------------------
__global__ __launch_bounds__(256) void cscanB_kernel(const unsigned* __restrict__ tot,
                                                     unsigned* __restrict__ boffG) {
    __shared__ unsigned wsum[4];
    __shared__ unsigned carrySh, chunkTot;
    const int t = threadIdx.x;
    if (t == 0) carrySh = 0u;
    __syncthreads();
    for (int c = 0; c < 4; ++c) {
        const int idx = c * 256 + t;
        const unsigned v = (idx < NBu) ? tot[idx] : 0u;
        const unsigned excl = block_exscan256(v, wsum, &chunkTot);
        if (idx < NBu) boffG[idx] = carrySh + excl;
        __syncthreads();
        if (t == 0) carrySh += chunkTot;
        __syncthreads();
    }
}

// ---------------- partition + hcomp ----------------------------------------
// Stage (dst,e) pairs into LDS bucket-ordered, flush coalesced into part[].
// Then compute h16[e] = fp16(relu(xw[src[e]] + ef[e] @ W1[:16])) coalesced.
__global__ __launch_bounds__(256) void part_hcomp_kernel(
    const int* __restrict__ dst, const unsigned* __restrict__ gstart,
    const unsigned* __restrict__ boffG,
    unsigned long long* __restrict__ part,
    const float* __restrict__ ef, const int* __restrict__ src,
    const float* __restrict__ xw, const float* __restrict__ W1,
    unsigned* __restrict__ h16)
{
    __shared__ unsigned long long st[EPB];   // 25 KB
    __shared__ unsigned lh[NBu], lstart[NBu], lc[NBu], gs[NBu];  // 12.5 KB
    __shared__ unsigned wsum[4], carrySh, chunkTot;
    const int t = threadIdx.x, b = blockIdx.x;
    for (int i = t; i < NBu; i += 256) lh[i] = 0u;
    __syncthreads();
    const int e0 = b * EPB;
#pragma unroll
    for (int it = 0; it < PITERS; ++it) {
        const int i = it * 256 + t;
        if (i < EPB) atomicAdd(&lh[(unsigned)dst[e0 + i] >> BSH], 1u);
    }
    if (t == 0) carrySh = 0u;
    __syncthreads();
    for (int c = 0; c < 4; ++c) {
        const int idx = c * 256 + t;
        const unsigned v = (idx < NBu) ? lh[idx] : 0u;
        const unsigned excl = block_exscan256(v, wsum, &chunkTot);
        if (idx < NBu) {
            const unsigned s0 = carrySh + excl;
            lstart[idx] = s0;
            lc[idx]     = s0;
            gs[idx]     = gstart[(size_t)b * NBu + idx] + boffG[idx];
        }
        __syncthreads();
        if (t == 0) carrySh += chunkTot;
        __syncthreads();
    }
    // stage into LDS (order within bucket race-dependent; max is order-invariant)
#pragma unroll
    for (int it = 0; it < PITERS; ++it) {
        const int i = it * 256 + t;
        if (i < EPB) {
            const int e = e0 + i;
            const unsigned d = (unsigned)dst[e];
            const unsigned p = atomicAdd(&lc[d >> BSH], 1u);
            st[p] = ((unsigned long long)d << 32) | (unsigned)e;
        }
    }
    __syncthreads();
    // coalesced flush
#pragma unroll
    for (int it = 0; it < PITERS; ++it) {
        const int i = it * 256 + t;
        if (i < EPB) {
            const unsigned long long pv = st[i];
            const unsigned bkt = (unsigned)(pv >> (32 + BSH));
            part[gs[bkt] + ((unsigned)i - lstart[bkt])] = pv;
        }
    }
    // hcomp (independent of staging; ef coalesced)
#pragma unroll
    for (int it = 0; it < PITERS; ++it) {
        const int i = it * 256 + t;
        if (i < EPB) {
            const int e = e0 + i;
            float in[16];
            const float4* efp = reinterpret_cast<const float4*>(ef) + (size_t)e * 4;
#pragma unroll
            for (int c = 0; c < 4; ++c) {
                float4 tv = efp[c];
                in[4*c+0]=tv.x; in[4*c+1]=tv.y; in[4*c+2]=tv.z; in[4*c+3]=tv.w;
            }
            const int s = src[e];
            float h[16];
            const float4* xp = reinterpret_cast<const float4*>(xw) + (size_t)s * 4;
#pragma unroll
            for (int c = 0; c < 4; ++c) {
                float4 tv = xp[c];
                h[4*c+0]=tv.x; h[4*c+1]=tv.y; h[4*c+2]=tv.z; h[4*c+3]=tv.w;
            }
#pragma unroll
            for (int ii = 0; ii < 16; ++ii)
#pragma unroll
                for (int k = 0; k < 16; ++k)
                    h[k] = fmaf(in[ii], W1[ii*16 + k], h[k]);
            unsigned wds[8];
#pragma unroll
            for (int k = 0; k < 8; ++k) {
                __half2 t2 = __floats2half2_rn(fmaxf(h[2*k], 0.0f), fmaxf(h[2*k+1], 0.0f));
                wds[k] = *reinterpret_cast<unsigned*>(&t2);
            }
            uint4* hp = reinterpret_cast<uint4*>(h16) + (size_t)e * 2;
            hp[0] = make_uint4(wds[0], wds[1], wds[2], wds[3]);
            hp[1] = make_uint4(wds[4], wds[5], wds[6], wds[7]);
        }
    }
}

// ---------------- fused edge+node: one block owns one 64-node bucket -------
// LDS rmax accumulation (no global atomics, no rkey, no init/decode passes),
// then node-update MLP + coalesced out write, all in-block.
__global__ __launch_bounds__(256) void fused_kernel(
    const unsigned long long* __restrict__ part,
    const unsigned* __restrict__ boffG, const unsigned* __restrict__ tot,
    const unsigned* __restrict__ h16,
    const float* __restrict__ W2, const float* __restrict__ b2,
    const float* __restrict__ x,
    const float* __restrict__ uW1, const float* __restrict__ ub1,
    const float* __restrict__ uW2, const float* __restrict__ ub2,
    float* __restrict__ out)
{
    __shared__ unsigned rmax[64][65];        // padded: decode reads conflict-free
    __shared__ unsigned mld[4][64][17];
    __shared__ int      dloc[4][64];
    const int tid = threadIdx.x, b = blockIdx.x;
    const int lane = tid & 63, w = tid >> 6;
    const unsigned base = boffG[b], cnt = tot[b];

    for (int i = tid; i < 64 * 65; i += 256)
        (&rmax[0][0])[i] = KEY_NEG_INF;
    __syncthreads();

    const int er = lane >> 4;   // 0..3
    const int jj = lane & 15;   // 0..15

    const int nIter = (int)((cnt + 255u) >> 8);
    for (int it = 0; it < nIter; ++it) {
        const unsigned slot = (unsigned)it * 256u + (unsigned)tid;
        const bool valid = slot < cnt;
        int nloc = 0;
        float h[16];
        if (valid) {
            const unsigned long long pv = part[base + slot];
            const int e = (int)(unsigned)pv;
            nloc = (int)((pv >> 32) & 63u);
            const uint4* hp = reinterpret_cast<const uint4*>(h16) + (size_t)e * 2;
            uint4 A = hp[0], B = hp[1];
            unsigned wd[8] = {A.x, A.y, A.z, A.w, B.x, B.y, B.z, B.w};
#pragma unroll
            for (int k = 0; k < 8; ++k) {
                __half2 t2 = *reinterpret_cast<const __half2*>(&wd[k]);
                float2 f = __half22float2(t2);
                h[2*k] = f.x; h[2*k+1] = f.y;
            }
        }
        dloc[w][lane] = nloc;

#pragma unroll
        for (int j0 = 0; j0 < 64; j0 += 16) {
            float m[16];
#pragma unroll
            for (int t16 = 0; t16 < 16; ++t16) m[t16] = b2[j0 + t16];
            if (valid) {
#pragma unroll
                for (int k = 0; k < 16; ++k)
#pragma unroll
                    for (int t16 = 0; t16 < 16; ++t16)
                        m[t16] = fmaf(h[k], W2[k*64 + j0 + t16], m[t16]);
            }
            wave_lds_fence();             // prior chunk's reads done
#pragma unroll
            for (int t16 = 0; t16 < 16; ++t16)
                mld[w][lane][t16] = valid ? fkey(m[t16]) : KEY_NEG_INF;
            wave_lds_fence();             // writes visible to wave
#pragma unroll
            for (int eg = 0; eg < 16; ++eg) {
                const int ee = (eg << 2) | er;
                atomicMax(&rmax[dloc[w][ee]][j0 + jj], mld[w][ee][jj]);
            }
        }
    }
    __syncthreads();   // all waves done accumulating rmax (nIter uniform)

    // ---- node phase: 4 threads per node (redundant hidden, own out-quarter)
    const int nl = tid & 63;
    const int qq = tid >> 6;
    const int v  = b * 64 + nl;
    if (v < N_NODES) {
        float h2[16];
#pragma unroll
        for (int k = 0; k < 16; ++k) h2[k] = ub1[k];
        const float4* xp = reinterpret_cast<const float4*>(x) + (size_t)v * 16;
#pragma unroll
        for (int c = 0; c < 16; ++c) {
            float4 tv = xp[c];
            const float xv[4] = {tv.x, tv.y, tv.z, tv.w};
#pragma unroll
            for (int u4 = 0; u4 < 4; ++u4) {
                const int row = 4*c + u4;
#pragma unroll
                for (int k = 0; k < 16; ++k)
                    h2[k] = fmaf(xv[u4], uW1[row*16 + k], h2[k]);
            }
        }
        for (int j = 0; j < 64; ++j) {
            const unsigned kk = rmax[nl][j];
            unsigned u = (kk & 0x80000000u) ? (kk ^ 0x80000000u) : ~kk;
            float f = __uint_as_float(u);
            if (!(f >= -3.402823466e38f && f <= 3.402823466e38f)) f = 0.0f;
#pragma unroll
            for (int k = 0; k < 16; ++k)
                h2[k] = fmaf(f, uW1[(64 + j)*16 + k], h2[k]);
        }
#pragma unroll
        for (int k = 0; k < 16; ++k) h2[k] = fmaxf(h2[k], 0.0f);
        float* op = out + (size_t)v * 64 + qq * 16;
#pragma unroll
        for (int c = 0; c < 4; ++c) {
            float oo[4];
#pragma unroll
            for (int u4 = 0; u4 < 4; ++u4) {
                const int col = qq*16 + 4*c + u4;
                float a = ub2[col];
#pragma unroll
                for (int k = 0; k < 16; ++k)
                    a = fmaf(h2[k], uW2[k*64 + col], a);
                oo[u4] = a;
            }
            float4 o; o.x=oo[0]; o.y=oo[1]; o.z=oo[2]; o.w=oo[3];
            reinterpret_cast<float4*>(op)[c] = o;
        }
    }
}

// =================== fallback tier (tiny ws): direct atomics ===============
__global__ __launch_bounds__(256) void init0_kernel(unsigned* __restrict__ rkey) {
    const int i = blockIdx.x * 256 + threadIdx.x;
    reinterpret_cast<uint4*>(rkey)[i] =
        make_uint4(KEY_NEG_INF, KEY_NEG_INF, KEY_NEG_INF, KEY_NEG_INF);
}

__global__ __launch_bounds__(64) void edge_kernel(
    const float* __restrict__ x, const float* __restrict__ ef,
    const int* __restrict__ src, const int* __restrict__ dst,
    const float* __restrict__ W1, const float* __restrict__ b1,
    const float* __restrict__ W2, const float* __restrict__ b2,
    unsigned* __restrict__ rkey)
{
    const int lane = threadIdx.x;
    const int e    = blockIdx.x * 64 + lane;
    __shared__ unsigned mld[64][17];
    __shared__ int      dld[64];
    float in[80];
    const float4* efp = reinterpret_cast<const float4*>(ef) + (size_t)e * 4;
#pragma unroll
    for (int c = 0; c < 4; ++c) {
        float4 tv = efp[c];
        in[4*c+0]=tv.x; in[4*c+1]=tv.y; in[4*c+2]=tv.z; in[4*c+3]=tv.w;
    }
    const int s = src[e];
    dld[lane] = dst[e];
    const float4* xp = reinterpret_cast<const float4*>(x) + (size_t)s * 16;
#pragma unroll
    for (int c = 0; c < 16; ++c) {
        float4 tv = xp[c];
        in[16+4*c+0]=tv.x; in[16+4*c+1]=tv.y; in[16+4*c+2]=tv.z; in[16+4*c+3]=tv.w;
    }
    float h[16];
#pragma unroll
    for (int k = 0; k < 16; ++k) h[k] = b1[k];
#pragma unroll
    for (int i = 0; i < 80; ++i)
#pragma unroll
        for (int k = 0; k < 16; ++k)
            h[k] = fmaf(in[i], W1[i*16 + k], h[k]);
#pragma unroll
    for (int k = 0; k < 16; ++k) h[k] = fmaxf(h[k], 0.0f);
    const int er = lane >> 4, jj = lane & 15;
#pragma unroll
    for (int j0 = 0; j0 < 64; j0 += 16) {
        float m[16];
#pragma unroll
        for (int t = 0; t < 16; ++t) m[t] = b2[j0 + t];
#pragma unroll
        for (int k = 0; k < 16; ++k)
#pragma unroll
            for (int t = 0; t < 16; ++t)
                m[t] = fmaf(h[k], W2[k*64 + j0 + t], m[t]);
        wave_lds_fence();
#pragma unroll
        for (int t = 0; t < 16; ++t) mld[lane][t] = fkey(m[t]);
        wave_lds_fence();
#pragma unroll
        for (int eg = 0; eg < 16; ++eg) {
            const int ee = (eg << 2) | er;
            atomicMax(&rkey[((size_t)dld[ee] << 6) + (unsigned)(j0 + jj)],
                      mld[ee][jj]);
        }
    }
}

// fallback node kernel: rkey/out alias d_out; each thread reads its own row first
__global__ __launch_bounds__(256) void node_kernel(
    const float* __restrict__ x, const unsigned* rkey,
    const float* __restrict__ W1, const float* __restrict__ b1,
    const float* __restrict__ W2, const float* __restrict__ b2,
    float* out)
{
    const int v = blockIdx.x * 256 + threadIdx.x;
    if (v >= N_NODES) return;
    float in[128];
    const float4* xp = reinterpret_cast<const float4*>(x) + (size_t)v * 16;
#pragma unroll
    for (int c = 0; c < 16; ++c) {
        float4 tv = xp[c];
        in[4*c+0]=tv.x; in[4*c+1]=tv.y; in[4*c+2]=tv.z; in[4*c+3]=tv.w;
    }
    const uint4* rp = reinterpret_cast<const uint4*>(rkey) + (size_t)v * 16;
#pragma unroll
    for (int c = 0; c < 16; ++c) {
        uint4 tv = rp[c];
        unsigned ks[4] = {tv.x, tv.y, tv.z, tv.w};
#pragma unroll
        for (int qq = 0; qq < 4; ++qq) {
            unsigned k = ks[qq];
            unsigned u = (k & 0x80000000u) ? (k ^ 0x80000000u) : ~k;
            float f = __uint_as_float(u);
            if (!(f >= -3.402823466e38f && f <= 3.402823466e38f)) f = 0.0f;
            in[64 + 4*c + qq] = f;
        }
    }
    float h[16];
#pragma unroll
    for (int k = 0; k < 16; ++k) h[k] = b1[k];
#pragma unroll
    for (int i = 0; i < 128; ++i)
#pragma unroll
        for (int k = 0; k < 16; ++k)
            h[k] = fmaf(in[i], W1[i*16 + k], h[k]);
#pragma unroll
    for (int k = 0; k < 16; ++k) h[k] = fmaxf(h[k], 0.0f);
    float* op = out + (size_t)v * 64;
#pragma unroll
    for (int c = 0; c < 16; ++c) {
        float oo[4];
#pragma unroll
        for (int qq = 0; qq < 4; ++qq) {
            float a = b2[4*c + qq];
#pragma unroll
            for (int k = 0; k < 16; ++k)
                a = fmaf(h[k], W2[k*64 + 4*c + qq], a);
            oo[qq] = a;
        }
        float4 o; o.x=oo[0]; o.y=oo[1]; o.z=oo[2]; o.w=oo[3];
        reinterpret_cast<float4*>(op)[c] = o;
    }
}

extern "C" void kernel_launch(void* const* d_in, const int* in_sizes, int n_in,
                              void* d_out, int out_size, void* d_ws, size_t ws_size,
                              hipStream_t stream) {
    const float* x   = (const float*)d_in[0];
    const float* ef  = (const float*)d_in[1];
    const int*   src = (const int*)d_in[2];
    const int*   dst = (const int*)d_in[3];
    const float* mW1 = (const float*)d_in[4];
    const float* mb1 = (const float*)d_in[5];
    const float* mW2 = (const float*)d_in[6];
    const float* mb2 = (const float*)d_in[7];
    const float* uW1 = (const float*)d_in[8];
    const float* ub1 = (const float*)d_in[9];
    const float* uW2 = (const float*)d_in[10];
    const float* ub2 = (const float*)d_in[11];

    float* out = (float*)d_out;

    // ws layout: part u64[E] | bcnt u32[PB*NBu] | gstart u32[PB*NBu] |
    //            tot u32[NBu] | boffG u32[NBu] | xw f32[50176*16] | h16 u32[E*8]
    unsigned long long* part = (unsigned long long*)d_ws;
    unsigned* bcnt   = (unsigned*)(part + N_EDGES);
    unsigned* gstart = bcnt + (size_t)PB * NBu;
    unsigned* tot    = gstart + (size_t)PB * NBu;
    unsigned* boffG  = tot + NBu;
    float*    xw     = (float*)(boffG + NBu);
    unsigned* h16    = (unsigned*)(xw + (size_t)50176 * 16);
    const size_t T1_NEEDED =
        (size_t)((char*)(h16 + (size_t)N_EDGES * 8) - (char*)d_ws);

    if (ws_size >= T1_NEEDED) {
        hipLaunchKernelGGL(chist_xw_kernel,  dim3(PB),  dim3(256), 0, stream,
                           dst, bcnt, x, mW1, mb1, xw);
        hipLaunchKernelGGL(cscanA_kernel,    dim3(NBu), dim3(256), 0, stream,
                           bcnt, gstart, tot);
        hipLaunchKernelGGL(cscanB_kernel,    dim3(1),   dim3(256), 0, stream,
                           tot, boffG);
        hipLaunchKernelGGL(part_hcomp_kernel, dim3(PB), dim3(256), 0, stream,
                           dst, gstart, boffG, part, ef, src, xw, mW1, h16);
        hipLaunchKernelGGL(fused_kernel,     dim3(NBu), dim3(256), 0, stream,
                           part, boffG, tot, h16, mW2, mb2,
                           x, uW1, ub1, uW2, ub2, out);
    } else {
        unsigned* rkey = (unsigned*)d_out;
        hipLaunchKernelGGL(init0_kernel, dim3(3125), dim3(256), 0, stream, rkey);
        hipLaunchKernelGGL(edge_kernel, dim3(12500), dim3(64), 0, stream,
                           x, ef, src, dst, mW1, mb1, mW2, mb2, rkey);
        hipLaunchKernelGGL(node_kernel, dim3((N_NODES + 255) / 256), dim3(256), 0, stream,
                           x, rkey, uW1, ub1, uW2, ub2, out);
    }
}

// Round 9
// 124.488 us; speedup vs baseline: 1.5238x; 1.5238x over previous
//
#include <hip/hip_runtime.h>
#include <hip/hip_fp16.h>

#define N_NODES 50000
#define N_EDGES 800000
// D_FEAT=64, D_EDGE=16, D_HID=16, D_MSG=64, D_OUT=64

#define NBu 1568   // 32-node buckets: 1568*32 = 50176 >= 50000
#define BSH 5      // bucket = dst >> 5
#define PB  512    // chist/partition blocks
#define EPB 1563   // edges per partition block (512*1563 = 800256 >= 800000)
#define PIT 7      // ceil(1563/256)
#define NCH 7      // scan chunks over NBu (7*256 = 1792 >= 1568)

__device__ __forceinline__ unsigned fkey(float f) {
    unsigned u = __float_as_uint(f);
    return (u & 0x80000000u) ? ~u : (u | 0x80000000u);
}
#define KEY_NEG_INF 0x007FFFFFu  // key(-inf)

// block-wide exclusive scan of 256 values (one per thread). Uniform call only.
__device__ __forceinline__ unsigned block_exscan256(unsigned v, unsigned* wsum,
                                                    unsigned* chunkTot) {
    const int t = threadIdx.x, lane = t & 63, w = t >> 6;
    unsigned inc = v;
#pragma unroll
    for (int d = 1; d < 64; d <<= 1) {
        unsigned n = __shfl_up(inc, d, 64);
        if (lane >= d) inc += n;
    }
    if (lane == 63) wsum[w] = inc;
    __syncthreads();
    unsigned woff = 0;
#pragma unroll
    for (int i = 0; i < 3; ++i) if (i < w) woff += wsum[i];
    if (chunkTot && t == 255) *chunkTot = woff + inc;
    __syncthreads();
    return woff + inc - v;
}

// ---------------- chist + xw ------------------------------------------------
// bcnt[b][bu] = count of this block's edges in bucket bu; xw = b1 + x @ W1[16:]
__global__ __launch_bounds__(256) void chist_xw_kernel(
    const int* __restrict__ dst, unsigned* __restrict__ bcnt,
    const float* __restrict__ x, const float* __restrict__ W1,
    const float* __restrict__ b1, float* __restrict__ xw)
{
    __shared__ unsigned lh[NBu];
    const int t = threadIdx.x, b = blockIdx.x;
    for (int i = t; i < NBu; i += 256) lh[i] = 0u;
    __syncthreads();
    const int e0 = b * EPB;
#pragma unroll
    for (int it = 0; it < PIT; ++it) {
        const int i = it * 256 + t;
        const int e = e0 + i;
        if (i < EPB && e < N_EDGES) atomicAdd(&lh[(unsigned)dst[e] >> BSH], 1u);
    }
    __syncthreads();
    for (int i = t; i < NBu; i += 256) bcnt[(size_t)b * NBu + i] = lh[i];

    if (b < 196) {   // 196*256 = 50176 >= 50000
        const int v = b * 256 + t;
        if (v < N_NODES) {
            float acc[16];
#pragma unroll
            for (int k = 0; k < 16; ++k) acc[k] = b1[k];
            const float4* xp = reinterpret_cast<const float4*>(x) + (size_t)v * 16;
#pragma unroll
            for (int c = 0; c < 16; ++c) {
                float4 tv = xp[c];
                const float xv[4] = {tv.x, tv.y, tv.z, tv.w};
#pragma unroll
                for (int q = 0; q < 4; ++q) {
                    const int row = 16 + 4 * c + q;
#pragma unroll
                    for (int k = 0; k < 16; ++k)
                        acc[k] = fmaf(xv[q], W1[row * 16 + k], acc[k]);
                }
            }
            float4* op = reinterpret_cast<float4*>(xw) + (size_t)v * 4;
#pragma unroll
            for (int c = 0; c < 4; ++c) {
                float4 o; o.x = acc[4*c]; o.y = acc[4*c+1]; o.z = acc[4*c+2]; o.w = acc[4*c+3];
                op[c] = o;
            }
        }
    }
}

// ---------------- cscanA: per-bucket exclusive scan over the PB blocks -----
__global__ __launch_bounds__(256) void cscanA_kernel(const unsigned* __restrict__ bcnt,
                                                     unsigned* __restrict__ gstart,
                                                     unsigned* __restrict__ tot) {
    __shared__ unsigned wsum[4];
    __shared__ unsigned carrySh, chunkTot;
    const int t = threadIdx.x, bu = blockIdx.x;
    if (t == 0) carrySh = 0u;
    __syncthreads();
#pragma unroll
    for (int c = 0; c < PB / 256; ++c) {
        const int k = c * 256 + t;
        const unsigned v = bcnt[(size_t)k * NBu + bu];
        const unsigned excl = block_exscan256(v, wsum, &chunkTot);
        gstart[(size_t)k * NBu + bu] = carrySh + excl;
        __syncthreads();
        if (t == 0) carrySh += chunkTot;
        __syncthreads();
    }
    if (t == 0) tot[bu] = carrySh;
}

// ---------------- cscanB: boffG = exscan(tot[NBu]) -------------------------
__global__ __launch_bounds__(256) void cscanB_kernel(const unsigned* __restrict__ tot,
                                                     unsigned* __restrict__ boffG) {
    __shared__ unsigned wsum[4];
    __shared__ unsigned carrySh, chunkTot;
    const int t = threadIdx.x;
    if (t == 0) carrySh = 0u;
    __syncthreads();
    for (int c = 0; c < NCH; ++c) {
        const int idx = c * 256 + t;
        const unsigned v = (idx < NBu) ? tot[idx] : 0u;
        const unsigned excl = block_exscan256(v, wsum, &chunkTot);
        if (idx < NBu) boffG[idx] = carrySh + excl;
        __syncthreads();
        if (t == 0) carrySh += chunkTot;
        __syncthreads();
    }
}

// ---------------- partition: LDS-staged bucket binning, coalesced flush ----
// part[pos] = (nloc<<20) | e   (u32; nloc = dst&31, e < 2^20)
__global__ __launch_bounds__(256) void partition_kernel(
    const int* __restrict__ dst, const unsigned* __restrict__ gstart,
    const unsigned* __restrict__ boffG, unsigned* __restrict__ part)
{
    __shared__ unsigned stV[EPB];            // 6.3 KB
    __shared__ unsigned short stB[EPB];      // 3.1 KB
    __shared__ unsigned lh[NBu], lstart[NBu], lc[NBu], gs[NBu];  // 25.1 KB
    __shared__ unsigned wsum[4], carrySh, chunkTot;
    const int t = threadIdx.x, b = blockIdx.x;
    for (int i = t; i < NBu; i += 256) lh[i] = 0u;
    __syncthreads();
    const int e0 = b * EPB;
#pragma unroll
    for (int it = 0; it < PIT; ++it) {
        const int i = it * 256 + t;
        const int e = e0 + i;
        if (i < EPB && e < N_EDGES) atomicAdd(&lh[(unsigned)dst[e] >> BSH], 1u);
    }
    if (t == 0) carrySh = 0u;
    __syncthreads();
    for (int c = 0; c < NCH; ++c) {
        const int idx = c * 256 + t;
        const unsigned v = (idx < NBu) ? lh[idx] : 0u;
        const unsigned excl = block_exscan256(v, wsum, &chunkTot);
        if (idx < NBu) {
            const unsigned s0 = carrySh + excl;
            lstart[idx] = s0;
            lc[idx]     = s0;
            gs[idx]     = gstart[(size_t)b * NBu + idx] + boffG[idx];
        }
        __syncthreads();
        if (t == 0) carrySh += chunkTot;
        __syncthreads();
    }
    // stage (order within bucket race-dependent; max is order-invariant)
#pragma unroll
    for (int it = 0; it < PIT; ++it) {
        const int i = it * 256 + t;
        const int e = e0 + i;
        if (i < EPB && e < N_EDGES) {
            const unsigned d = (unsigned)dst[e];
            const unsigned bkt = d >> BSH;
            const unsigned p = atomicAdd(&lc[bkt], 1u);
            stV[p] = ((d & 31u) << 20) | (unsigned)e;
            stB[p] = (unsigned short)bkt;
        }
    }
    __syncthreads();
    // coalesced flush
    const int lim = min(EPB, N_EDGES - e0);
#pragma unroll
    for (int it = 0; it < PIT; ++it) {
        const int i = it * 256 + t;
        if (i < lim) {
            const unsigned bkt = stB[i];
            part[gs[bkt] + ((unsigned)i - lstart[bkt])] = stV[i];
        }
    }
}

// ---------------- hcomp: h16[e] = fp16(relu(xw[src[e]] + ef[e]@W1[:16])) ---
__global__ __launch_bounds__(256) void hcomp_kernel(
    const float* __restrict__ ef, const int* __restrict__ src,
    const float* __restrict__ xw, const float* __restrict__ W1,
    unsigned* __restrict__ h16)
{
    const int e = blockIdx.x * 256 + threadIdx.x;  // 3125*256 = 800000 exact
    float in[16];
    const float4* efp = reinterpret_cast<const float4*>(ef) + (size_t)e * 4;
#pragma unroll
    for (int c = 0; c < 4; ++c) {
        float4 tv = efp[c];
        in[4*c+0]=tv.x; in[4*c+1]=tv.y; in[4*c+2]=tv.z; in[4*c+3]=tv.w;
    }
    const int s = src[e];
    float h[16];
    const float4* xp = reinterpret_cast<const float4*>(xw) + (size_t)s * 4;
#pragma unroll
    for (int c = 0; c < 4; ++c) {
        float4 tv = xp[c];
        h[4*c+0]=tv.x; h[4*c+1]=tv.y; h[4*c+2]=tv.z; h[4*c+3]=tv.w;
    }
#pragma unroll
    for (int i = 0; i < 16; ++i)
#pragma unroll
        for (int k = 0; k < 16; ++k)
            h[k] = fmaf(in[i], W1[i*16 + k], h[k]);
    unsigned wds[8];
#pragma unroll
    for (int k = 0; k < 8; ++k) {
        __half2 t2 = __floats2half2_rn(fmaxf(h[2*k], 0.0f), fmaxf(h[2*k+1], 0.0f));
        wds[k] = *reinterpret_cast<unsigned*>(&t2);
    }
    uint4* hp = reinterpret_cast<uint4*>(h16) + (size_t)e * 2;
    hp[0] = make_uint4(wds[0], wds[1], wds[2], wds[3]);
    hp[1] = make_uint4(wds[4], wds[5], wds[6], wds[7]);
}

// ---------------- reduce+node: one block owns one 32-node bucket -----------
// Direct LDS atomicMax (no transpose: LDS needs no line coalescing; stride-65
// makes conflicts ~2-way = free). Then node MLP, 4 threads/node, out coalesced.
__global__ __launch_bounds__(256) void reduce_fused_kernel(
    const unsigned* __restrict__ part,
    const unsigned* __restrict__ boffG, const unsigned* __restrict__ tot,
    const unsigned* __restrict__ h16,
    const float* __restrict__ W2, const float* __restrict__ b2,
    const float* __restrict__ x,
    const float* __restrict__ uW1, const float* __restrict__ ub1,
    const float* __restrict__ uW2, const float* __restrict__ ub2,
    float* __restrict__ out)
{
    __shared__ unsigned rmax[32][65];   // 8.3 KB, padded
    __shared__ float    xsh[32][65];    // 8.3 KB, padded
    const int tid = threadIdx.x, b = blockIdx.x;
    const unsigned base = boffG[b], cnt = tot[b];
    const int v0 = b * 32;

    for (int i = tid; i < 32 * 65; i += 256) (&rmax[0][0])[i] = KEY_NEG_INF;
    // stage x rows for the node phase (2-way LDS write aliasing = free)
    for (int i = tid; i < 512; i += 256) {
        const int row = i >> 4, c = i & 15;
        float4 tv = (v0 + row < N_NODES)
            ? reinterpret_cast<const float4*>(x)[(size_t)(v0 + row) * 16 + c]
            : make_float4(0.f, 0.f, 0.f, 0.f);
        xsh[row][c*4+0] = tv.x; xsh[row][c*4+1] = tv.y;
        xsh[row][c*4+2] = tv.z; xsh[row][c*4+3] = tv.w;
    }
    __syncthreads();

    const int nIter = (int)((cnt + 255u) >> 8);
    for (int it = 0; it < nIter; ++it) {
        const unsigned slot = (unsigned)it * 256u + (unsigned)tid;
        if (slot < cnt) {
            const unsigned pv = part[base + slot];
            const int e    = (int)(pv & 0xFFFFFu);
            const int nloc = (int)(pv >> 20);
            float h[16];
            {
                const uint4* hp = reinterpret_cast<const uint4*>(h16) + (size_t)e * 2;
                uint4 A = hp[0], B = hp[1];
                unsigned wd[8] = {A.x, A.y, A.z, A.w, B.x, B.y, B.z, B.w};
#pragma unroll
                for (int k = 0; k < 8; ++k) {
                    __half2 t2 = *reinterpret_cast<const __half2*>(&wd[k]);
                    float2 f = __half22float2(t2);
                    h[2*k] = f.x; h[2*k+1] = f.y;
                }
            }
#pragma unroll
            for (int j0 = 0; j0 < 64; j0 += 16) {
                float m[16];
#pragma unroll
                for (int t16 = 0; t16 < 16; ++t16) m[t16] = b2[j0 + t16];
#pragma unroll
                for (int k = 0; k < 16; ++k)
#pragma unroll
                    for (int t16 = 0; t16 < 16; ++t16)
                        m[t16] = fmaf(h[k], W2[k*64 + j0 + t16], m[t16]);
#pragma unroll
                for (int t16 = 0; t16 < 16; ++t16)
                    atomicMax(&rmax[nloc][j0 + t16], fkey(m[t16]));
            }
        }
    }
    __syncthreads();

    // ---- node phase: 4 threads per node (tid<128), each owns 16 out cols --
    if (tid < 128) {
        const int nl = tid >> 2;        // 0..31
        const int qq = tid & 3;         // 0..3
        const int v  = v0 + nl;
        if (v < N_NODES) {
            float h2[16];
#pragma unroll
            for (int k = 0; k < 16; ++k) h2[k] = ub1[k];
            for (int row = 0; row < 64; ++row) {
                const float xv = xsh[nl][row];
#pragma unroll
                for (int k = 0; k < 16; ++k)
                    h2[k] = fmaf(xv, uW1[row*16 + k], h2[k]);
            }
            for (int j = 0; j < 64; ++j) {
                const unsigned kk = rmax[nl][j];
                unsigned u = (kk & 0x80000000u) ? (kk ^ 0x80000000u) : ~kk;
                float f = __uint_as_float(u);
                if (!(f >= -3.402823466e38f && f <= 3.402823466e38f)) f = 0.0f;
#pragma unroll
                for (int k = 0; k < 16; ++k)
                    h2[k] = fmaf(f, uW1[(64 + j)*16 + k], h2[k]);
            }
#pragma unroll
            for (int k = 0; k < 16; ++k) h2[k] = fmaxf(h2[k], 0.0f);
            float* op = out + (size_t)v * 64 + qq * 16;
#pragma unroll
            for (int c = 0; c < 4; ++c) {
                float oo[4];
#pragma unroll
                for (int u4 = 0; u4 < 4; ++u4) {
                    const int col = qq*16 + 4*c + u4;
                    float a = ub2[col];
#pragma unroll
                    for (int k = 0; k < 16; ++k)
                        a = fmaf(h2[k], uW2[k*64 + col], a);
                    oo[u4] = a;
                }
                float4 o; o.x=oo[0]; o.y=oo[1]; o.z=oo[2]; o.w=oo[3];
                reinterpret_cast<float4*>(op)[c] = o;
            }
        }
    }
}

// =================== fallback tier (tiny ws): direct atomics ===============
__device__ __forceinline__ void wave_lds_fence() {
    asm volatile("s_waitcnt lgkmcnt(0)" ::: "memory");
    __builtin_amdgcn_sched_barrier(0);
}

__global__ __launch_bounds__(256) void init0_kernel(unsigned* __restrict__ rkey) {
    const int i = blockIdx.x * 256 + threadIdx.x;
    reinterpret_cast<uint4*>(rkey)[i] =
        make_uint4(KEY_NEG_INF, KEY_NEG_INF, KEY_NEG_INF, KEY_NEG_INF);
}

__global__ __launch_bounds__(64) void edge_kernel(
    const float* __restrict__ x, const float* __restrict__ ef,
    const int* __restrict__ src, const int* __restrict__ dst,
    const float* __restrict__ W1, const float* __restrict__ b1,
    const float* __restrict__ W2, const float* __restrict__ b2,
    unsigned* __restrict__ rkey)
{
    const int lane = threadIdx.x;
    const int e    = blockIdx.x * 64 + lane;
    __shared__ unsigned mld[64][17];
    __shared__ int      dld[64];
    float in[80];
    const float4* efp = reinterpret_cast<const float4*>(ef) + (size_t)e * 4;
#pragma unroll
    for (int c = 0; c < 4; ++c) {
        float4 tv = efp[c];
        in[4*c+0]=tv.x; in[4*c+1]=tv.y; in[4*c+2]=tv.z; in[4*c+3]=tv.w;
    }
    const int s = src[e];
    dld[lane] = dst[e];
    const float4* xp = reinterpret_cast<const float4*>(x) + (size_t)s * 16;
#pragma unroll
    for (int c = 0; c < 16; ++c) {
        float4 tv = xp[c];
        in[16+4*c+0]=tv.x; in[16+4*c+1]=tv.y; in[16+4*c+2]=tv.z; in[16+4*c+3]=tv.w;
    }
    float h[16];
#pragma unroll
    for (int k = 0; k < 16; ++k) h[k] = b1[k];
#pragma unroll
    for (int i = 0; i < 80; ++i)
#pragma unroll
        for (int k = 0; k < 16; ++k)
            h[k] = fmaf(in[i], W1[i*16 + k], h[k]);
#pragma unroll
    for (int k = 0; k < 16; ++k) h[k] = fmaxf(h[k], 0.0f);
    const int er = lane >> 4, jj = lane & 15;
#pragma unroll
    for (int j0 = 0; j0 < 64; j0 += 16) {
        float m[16];
#pragma unroll
        for (int t = 0; t < 16; ++t) m[t] = b2[j0 + t];
#pragma unroll
        for (int k = 0; k < 16; ++k)
#pragma unroll
            for (int t = 0; t < 16; ++t)
                m[t] = fmaf(h[k], W2[k*64 + j0 + t], m[t]);
        wave_lds_fence();
#pragma unroll
        for (int t = 0; t < 16; ++t) mld[lane][t] = fkey(m[t]);
        wave_lds_fence();
#pragma unroll
        for (int eg = 0; eg < 16; ++eg) {
            const int ee = (eg << 2) | er;
            atomicMax(&rkey[((size_t)dld[ee] << 6) + (unsigned)(j0 + jj)],
                      mld[ee][jj]);
        }
    }
}

__global__ __launch_bounds__(256) void node_kernel(
    const float* __restrict__ x, const unsigned* rkey,
    const float* __restrict__ W1, const float* __restrict__ b1,
    const float* __restrict__ W2, const float* __restrict__ b2,
    float* out)
{
    const int v = blockIdx.x * 256 + threadIdx.x;
    if (v >= N_NODES) return;
    float in[128];
    const float4* xp = reinterpret_cast<const float4*>(x) + (size_t)v * 16;
#pragma unroll
    for (int c = 0; c < 16; ++c) {
        float4 tv = xp[c];
        in[4*c+0]=tv.x; in[4*c+1]=tv.y; in[4*c+2]=tv.z; in[4*c+3]=tv.w;
    }
    const uint4* rp = reinterpret_cast<const uint4*>(rkey) + (size_t)v * 16;
#pragma unroll
    for (int c = 0; c < 16; ++c) {
        uint4 tv = rp[c];
        unsigned ks[4] = {tv.x, tv.y, tv.z, tv.w};
#pragma unroll
        for (int qq = 0; qq < 4; ++qq) {
            unsigned k = ks[qq];
            unsigned u = (k & 0x80000000u) ? (k ^ 0x80000000u) : ~k;
            float f = __uint_as_float(u);
            if (!(f >= -3.402823466e38f && f <= 3.402823466e38f)) f = 0.0f;
            in[64 + 4*c + qq] = f;
        }
    }
    float h[16];
#pragma unroll
    for (int k = 0; k < 16; ++k) h[k] = b1[k];
#pragma unroll
    for (int i = 0; i < 128; ++i)
#pragma unroll
        for (int k = 0; k < 16; ++k)
            h[k] = fmaf(in[i], W1[i*16 + k], h[k]);
#pragma unroll
    for (int k = 0; k < 16; ++k) h[k] = fmaxf(h[k], 0.0f);
    float* op = out + (size_t)v * 64;
#pragma unroll
    for (int c = 0; c < 16; ++c) {
        float oo[4];
#pragma unroll
        for (int qq = 0; qq < 4; ++qq) {
            float a = b2[4*c + qq];
#pragma unroll
            for (int k = 0; k < 16; ++k)
                a = fmaf(h[k], W2[k*64 + 4*c + qq], a);
            oo[qq] = a;
        }
        float4 o; o.x=oo[0]; o.y=oo[1]; o.z=oo[2]; o.w=oo[3];
        reinterpret_cast<float4*>(op)[c] = o;
    }
}

extern "C" void kernel_launch(void* const* d_in, const int* in_sizes, int n_in,
                              void* d_out, int out_size, void* d_ws, size_t ws_size,
                              hipStream_t stream) {
    const float* x   = (const float*)d_in[0];
    const float* ef  = (const float*)d_in[1];
    const int*   src = (const int*)d_in[2];
    const int*   dst = (const int*)d_in[3];
    const float* mW1 = (const float*)d_in[4];
    const float* mb1 = (const float*)d_in[5];
    const float* mW2 = (const float*)d_in[6];
    const float* mb2 = (const float*)d_in[7];
    const float* uW1 = (const float*)d_in[8];
    const float* ub1 = (const float*)d_in[9];
    const float* uW2 = (const float*)d_in[10];
    const float* ub2 = (const float*)d_in[11];

    float* out = (float*)d_out;

    // ws layout: part u32[E] | bcnt u32[PB*NBu] | gstart u32[PB*NBu] |
    //            tot u32[NBu] | boffG u32[NBu] | xw f32[50176*16] | h16 u32[E*8]
    unsigned* part   = (unsigned*)d_ws;
    unsigned* bcnt   = part + N_EDGES;
    unsigned* gstart = bcnt + (size_t)PB * NBu;
    unsigned* tot    = gstart + (size_t)PB * NBu;
    unsigned* boffG  = tot + NBu;
    float*    xw     = (float*)(boffG + NBu);
    unsigned* h16    = (unsigned*)(xw + (size_t)50176 * 16);
    const size_t T1_NEEDED =
        (size_t)((char*)(h16 + (size_t)N_EDGES * 8) - (char*)d_ws);  // ~38.5 MB

    if (ws_size >= T1_NEEDED) {
        hipLaunchKernelGGL(chist_xw_kernel,  dim3(PB),   dim3(256), 0, stream,
                           dst, bcnt, x, mW1, mb1, xw);
        hipLaunchKernelGGL(cscanA_kernel,    dim3(NBu),  dim3(256), 0, stream,
                           bcnt, gstart, tot);
        hipLaunchKernelGGL(cscanB_kernel,    dim3(1),    dim3(256), 0, stream,
                           tot, boffG);
        hipLaunchKernelGGL(partition_kernel, dim3(PB),   dim3(256), 0, stream,
                           dst, gstart, boffG, part);
        hipLaunchKernelGGL(hcomp_kernel,     dim3(3125), dim3(256), 0, stream,
                           ef, src, xw, mW1, h16);
        hipLaunchKernelGGL(reduce_fused_kernel, dim3(NBu), dim3(256), 0, stream,
                           part, boffG, tot, h16, mW2, mb2,
                           x, uW1, ub1, uW2, ub2, out);
    } else {
        unsigned* rkey = (unsigned*)d_out;
        hipLaunchKernelGGL(init0_kernel, dim3(3125), dim3(256), 0, stream, rkey);
        hipLaunchKernelGGL(edge_kernel, dim3(12500), dim3(64), 0, stream,
                           x, ef, src, dst, mW1, mb1, mW2, mb2, rkey);
        hipLaunchKernelGGL(node_kernel, dim3((N_NODES + 255) / 256), dim3(256), 0, stream,
                           x, rkey, uW1, ub1, uW2, ub2, out);
    }
}